// Round 3
// baseline (375.529 us; speedup 1.0000x reference)
//
#include <hip/hip_runtime.h>
#include <stdint.h>

#define B_ 16
#define N_ 1024
#define C_ 256
#define LST 1032   // P_lds row stride in shorts (16B-aligned rows)

typedef __attribute__((ext_vector_type(8))) short short8;
typedef __attribute__((ext_vector_type(4))) float f32x4;

__device__ __forceinline__ short f2bf(float f) {
  uint32_t u = __builtin_bit_cast(uint32_t, f);
  u += 0x7fffu + ((u >> 16) & 1u);   // RNE to bf16
  return (short)(u >> 16);
}

// cast Q (blockIdx.y==0) or K (==1) to bf16, 8 elems/thread
__global__ __launch_bounds__(256) void cast2_kernel(const float* __restrict__ Q,
                                                    const float* __restrict__ K,
                                                    short* __restrict__ Qbf,
                                                    short* __restrict__ Kbf) {
  const float* in = blockIdx.y ? K : Q;
  short* out = blockIdx.y ? Kbf : Qbf;
  size_t i = (size_t)blockIdx.x * 256 + threadIdx.x;
  const float4* p = (const float4*)(in + i * 8);
  float4 a = p[0], b = p[1];
  short8 r;
  r[0] = f2bf(a.x); r[1] = f2bf(a.y); r[2] = f2bf(a.z); r[3] = f2bf(a.w);
  r[4] = f2bf(b.x); r[5] = f2bf(b.y); r[6] = f2bf(b.z); r[7] = f2bf(b.w);
  *(short8*)(out + i * 8) = r;
}

// V (B,N,C) f32 -> Vt (B,C,N) bf16, 64x64 tiles, short8 stores
__global__ __launch_bounds__(256) void vt_kernel(const float* __restrict__ V,
                                                 short* __restrict__ Vt) {
  __shared__ short t[64][72];
  int b = blockIdx.z;
  int nb = blockIdx.x * 64;
  int cb = blockIdx.y * 64;
  int tx = threadIdx.x & 15;   // c quad (4 floats)
  int ty = threadIdx.x >> 4;   // n row 0..15
#pragma unroll
  for (int i = 0; i < 4; i++) {
    int n = ty + 16 * i;
    float4 v = *(const float4*)&V[((size_t)b * N_ + nb + n) * C_ + cb + tx * 4];
    t[tx * 4 + 0][n] = f2bf(v.x);
    t[tx * 4 + 1][n] = f2bf(v.y);
    t[tx * 4 + 2][n] = f2bf(v.z);
    t[tx * 4 + 3][n] = f2bf(v.w);
  }
  __syncthreads();
  int n0 = (threadIdx.x & 7) * 8;
  int c0 = threadIdx.x >> 3;   // 0..31
#pragma unroll
  for (int i = 0; i < 2; i++) {
    int c = c0 + 32 * i;
    short8 s = *(const short8*)&t[c][n0];
    *(short8*)&Vt[((size_t)b * C_ + cb + c) * N_ + nb + n0] = s;
  }
}

// Fused attention. Block = 16 q rows of one batch; wave w owns k in [w*256, w*256+256).
// QK^T computed TRANSPOSED: acc[kt][r] = S^T[k = w*256+kt*16+quad*4+r][q = q0+l15]
// so dis/mask/p_attn access 4 consecutive k per lane -> dwordx4.
__global__ __launch_bounds__(256, 4) void attn_kernel(
    const short* __restrict__ Qbf, const short* __restrict__ Kbf,
    const short* __restrict__ Vt, const float* __restrict__ dis,
    const int* __restrict__ mask, float* __restrict__ p_attn,
    float* __restrict__ p_val) {
  __shared__ short P_lds[16 * LST];
  __shared__ float redm[4][16];
  __shared__ float reds[4][16];

  int gid = blockIdx.x;
  int b = gid & 15;            // consecutive blocks -> different batches (XCD spread)
  int q0 = (gid >> 4) * 16;
  int tid = threadIdx.x;
  int w = tid >> 6;
  int lane = tid & 63;
  int l15 = lane & 15;
  int quad = lane >> 4;

  f32x4 z = {0.f, 0.f, 0.f, 0.f};
  f32x4 acc[16];
#pragma unroll
  for (int i = 0; i < 16; i++) acc[i] = z;

  const short* Qp = Qbf + ((size_t)b * N_ + q0 + l15) * C_ + quad * 8;       // B-frag (n=q)
  const short* Kp = Kbf + ((size_t)b * N_ + w * 256 + l15) * C_ + quad * 8;  // A-frag (m=k)

#pragma unroll
  for (int cs = 0; cs < C_; cs += 32) {
    short8 bq = *(const short8*)(Qp + cs);
#pragma unroll
    for (int kt = 0; kt < 16; kt++) {
      short8 ak = *(const short8*)(Kp + (size_t)kt * 16 * C_ + cs);
      acc[kt] = __builtin_amdgcn_mfma_f32_16x16x32_bf16(ak, bq, acc[kt], 0, 0, 0);
    }
  }

  // ---- + dis, mask, scale (dwordx4), in-lane row max ----
  size_t base = ((size_t)b * N_ + q0 + l15) * N_ + w * 256 + quad * 4;

  float m = -3.0e38f;
#pragma unroll
  for (int kc = 0; kc < 4; kc++) {
    float4 dv[4];
    int4 mv[4];
#pragma unroll
    for (int j = 0; j < 4; j++)
      dv[j] = *(const float4*)(dis + base + (size_t)(kc * 4 + j) * 16);
#pragma unroll
    for (int j = 0; j < 4; j++)
      mv[j] = *(const int4*)(mask + base + (size_t)(kc * 4 + j) * 16);
#pragma unroll
    for (int j = 0; j < 4; j++) {
      int kt = kc * 4 + j;
      acc[kt][0] = mv[j].x ? -3.0e38f : (acc[kt][0] + dv[j].x) * 0.0625f;
      acc[kt][1] = mv[j].y ? -3.0e38f : (acc[kt][1] + dv[j].y) * 0.0625f;
      acc[kt][2] = mv[j].z ? -3.0e38f : (acc[kt][2] + dv[j].z) * 0.0625f;
      acc[kt][3] = mv[j].w ? -3.0e38f : (acc[kt][3] + dv[j].w) * 0.0625f;
      m = fmaxf(m, fmaxf(fmaxf(acc[kt][0], acc[kt][1]),
                         fmaxf(acc[kt][2], acc[kt][3])));
    }
  }

  // all 64 values in this lane belong to q = q0+l15; reduce across quads then waves
  m = fmaxf(m, __shfl_xor(m, 16));
  m = fmaxf(m, __shfl_xor(m, 32));
  if (lane < 16) redm[w][lane] = m;
  __syncthreads();
  float M = fmaxf(fmaxf(redm[0][l15], redm[1][l15]),
                  fmaxf(redm[2][l15], redm[3][l15]));

  float sum = 0.f;
#pragma unroll
  for (int kt = 0; kt < 16; kt++) {
#pragma unroll
    for (int r = 0; r < 4; r++) {
      float e = __expf(acc[kt][r] - M);
      acc[kt][r] = e;
      sum += e;
    }
  }
  sum += __shfl_xor(sum, 16);
  sum += __shfl_xor(sum, 32);
  if (lane < 16) reds[w][lane] = sum;
  __syncthreads();
  float inv = 1.0f / (reds[0][l15] + reds[1][l15] + reds[2][l15] + reds[3][l15]);

  // ---- write p_attn (float4) + P into LDS (bf16, ds_write_b64) ----
#pragma unroll
  for (int kt = 0; kt < 16; kt++) {
    float4 p;
    p.x = acc[kt][0] * inv;
    p.y = acc[kt][1] * inv;
    p.z = acc[kt][2] * inv;
    p.w = acc[kt][3] * inv;
    *(float4*)(p_attn + base + (size_t)kt * 16) = p;
    short4 pb;
    pb.x = f2bf(p.x); pb.y = f2bf(p.y); pb.z = f2bf(p.z); pb.w = f2bf(p.w);
    *(short4*)&P_lds[l15 * LST + w * 256 + kt * 16 + quad * 4] = pb;
  }
  __syncthreads();

  // ---- PV: A = P (m=q from LDS rows), B = Vt (n=c), out cols w*64..w*64+63 ----
  f32x4 o[4];
#pragma unroll
  for (int i = 0; i < 4; i++) o[i] = z;
  const short* Vp = Vt + ((size_t)b * C_ + w * 64 + l15) * N_ + quad * 8;

#pragma unroll 4
  for (int ks = 0; ks < N_; ks += 32) {
    short8 a = *(const short8*)&P_lds[l15 * LST + ks + quad * 8];
#pragma unroll
    for (int ct = 0; ct < 4; ct++) {
      short8 bv = *(const short8*)(Vp + (size_t)ct * 16 * N_ + ks);
      o[ct] = __builtin_amdgcn_mfma_f32_16x16x32_bf16(a, bv, o[ct], 0, 0, 0);
    }
  }

#pragma unroll
  for (int ct = 0; ct < 4; ct++)
#pragma unroll
    for (int r = 0; r < 4; r++)
      p_val[((size_t)b * N_ + q0 + quad * 4 + r) * C_ + w * 64 + ct * 16 + l15] =
          o[ct][r];
}

extern "C" void kernel_launch(void* const* d_in, const int* in_sizes, int n_in,
                              void* d_out, int out_size, void* d_ws, size_t ws_size,
                              hipStream_t stream) {
  const float* Q   = (const float*)d_in[0];
  const float* K   = (const float*)d_in[1];
  const float* V   = (const float*)d_in[2];
  const int* mask  = (const int*)d_in[3];
  const float* dis = (const float*)d_in[4];

  float* out = (float*)d_out;
  float* p_val  = out;                          // (B,N,C)
  float* p_attn = out + (size_t)B_ * N_ * C_;   // (B,N,N)

  const size_t nelem = (size_t)B_ * N_ * C_;    // 4,194,304
  short* Qbf = (short*)d_ws;
  short* Kbf = Qbf + nelem;
  short* Vt  = Kbf + nelem;

  cast2_kernel<<<dim3((unsigned)(nelem / 8 / 256), 2), 256, 0, stream>>>(Q, K, Qbf, Kbf);
  vt_kernel<<<dim3(N_ / 64, C_ / 64, B_), 256, 0, stream>>>(V, Vt);
  attn_kernel<<<dim3(B_ * (N_ / 16)), 256, 0, stream>>>(Qbf, Kbf, Vt, dis, mask,
                                                        p_attn, p_val);
}

// Round 4
// 294.609 us; speedup vs baseline: 1.2747x; 1.2747x over previous
//
#include <hip/hip_runtime.h>
#include <stdint.h>

#define B_ 16
#define N_ 1024
#define C_ 256
#define PSTRIDE 1032          // P_lds row stride in shorts
#define WBUF 16640            // per-wave staging bytes (2 x 8320)

typedef __attribute__((ext_vector_type(8))) short short8;
typedef __attribute__((ext_vector_type(4))) float f32x4;
typedef __attribute__((ext_vector_type(4))) int i32x4;

__device__ __forceinline__ short f2bf(float f) {
  uint32_t u = __builtin_bit_cast(uint32_t, f);
  u += 0x7fffu + ((u >> 16) & 1u);   // RNE to bf16
  return (short)(u >> 16);
}

// async global->LDS, 16 B per lane; lds dest = uniform base + lane*16
__device__ __forceinline__ void g2l16(const void* gptr, void* lptr) {
  __builtin_amdgcn_global_load_lds(
      (const __attribute__((address_space(1))) uint32_t*)gptr,
      (__attribute__((address_space(3))) uint32_t*)lptr, 16, 0, 0);
}

// s_waitcnt imms (gfx9 encoding): vmcnt[3:0]|expcnt<<4|lgkmcnt<<8|vmcnt[5:4]<<14
#define WC_VM0   0x0F70   // vmcnt(0), others no-wait
#define WC_VM8   0x0F78   // vmcnt(8)

// prelude: blocks [0,2048): cast K f32->bf16 ; blocks [2048,3072): V -> Vt bf16
__global__ __launch_bounds__(256) void prep_kernel(const float* __restrict__ K,
                                                   const float* __restrict__ V,
                                                   short* __restrict__ Kbf,
                                                   short* __restrict__ Vt) {
  int bx = blockIdx.x;
  if (bx < 2048) {
    size_t i = (size_t)bx * 256 + threadIdx.x;
    const float4* p = (const float4*)(K + i * 8);
    float4 a = p[0], b = p[1];
    short8 r;
    r[0] = f2bf(a.x); r[1] = f2bf(a.y); r[2] = f2bf(a.z); r[3] = f2bf(a.w);
    r[4] = f2bf(b.x); r[5] = f2bf(b.y); r[6] = f2bf(b.z); r[7] = f2bf(b.w);
    *(short8*)(Kbf + i * 8) = r;
  } else {
    bx -= 2048;
    __shared__ short t[64][72];
    int b = bx >> 6;
    int nb = (bx & 15) * 64;
    int cb = ((bx >> 4) & 3) * 64;
    int tx = threadIdx.x & 15;
    int ty = threadIdx.x >> 4;
#pragma unroll
    for (int i = 0; i < 4; i++) {
      int n = ty + 16 * i;
      float4 v = *(const float4*)&V[((size_t)b * N_ + nb + n) * C_ + cb + tx * 4];
      t[tx * 4 + 0][n] = f2bf(v.x);
      t[tx * 4 + 1][n] = f2bf(v.y);
      t[tx * 4 + 2][n] = f2bf(v.z);
      t[tx * 4 + 3][n] = f2bf(v.w);
    }
    __syncthreads();
    int n0 = (threadIdx.x & 7) * 8;
    int c0 = threadIdx.x >> 3;
#pragma unroll
    for (int i = 0; i < 2; i++) {
      int c = c0 + 32 * i;
      short8 s = *(const short8*)&t[c][n0];
      *(short8*)&Vt[((size_t)b * C_ + cb + c) * N_ + nb + n0] = s;
    }
  }
}

// Fused attention. Block = 16 q rows of one batch; wave w owns k in [w*256, w*256+256).
// S computed transposed: acc[kt][r] = S^T[k = w*256+kt*16+quad*4+r][q = q0+l15].
__global__ __launch_bounds__(256) void attn_kernel(
    const short* __restrict__ Kbf, const short* __restrict__ Vt,
    const float* __restrict__ Qf32, const float* __restrict__ dis,
    const int* __restrict__ mask, float* __restrict__ p_attn,
    float* __restrict__ p_val) {
  __shared__ char smem[4 * WBUF];   // per-wave K/dis/mask staging; P_lds aliases [0,33024)
  __shared__ float redm[4][16];
  __shared__ float reds[4][16];

  int gid = blockIdx.x;
  int b = gid & 15;                 // round-robin batches across XCDs
  int q0 = (gid >> 4) * 16;
  int tid = threadIdx.x;
  int w = tid >> 6;
  int lane = tid & 63;
  int l15 = lane & 15;
  int quad = lane >> 4;

  char* kbuf = smem + w * WBUF;
  short* P_lds = (short*)smem;

  // ---- Q fragments (one-time, f32 global, convert in reg) ----
  short8 qf[8];
  const float* Qp = Qf32 + ((size_t)b * N_ + q0 + l15) * C_ + quad * 8;
#pragma unroll
  for (int cs = 0; cs < 8; cs++) {
    float4 a = *(const float4*)(Qp + cs * 32);
    float4 c = *(const float4*)(Qp + cs * 32 + 4);
    short8 r;
    r[0] = f2bf(a.x); r[1] = f2bf(a.y); r[2] = f2bf(a.z); r[3] = f2bf(a.w);
    r[4] = f2bf(c.x); r[5] = f2bf(c.y); r[6] = f2bf(c.z); r[7] = f2bf(c.w);
    qf[cs] = r;
  }

  // ---- QK^T with double-buffered LDS-staged K ----
  f32x4 z = {0.f, 0.f, 0.f, 0.f};
  f32x4 acc[16];
#pragma unroll
  for (int i = 0; i < 16; i++) acc[i] = z;

  const short* Kp = Kbf + ((size_t)b * N_ + w * 256) * C_;  // wave's 256 k-rows

#define STAGE_K(kt, half)                                                  \
  {                                                                        \
    _Pragma("unroll") for (int p = 0; p < 8; p++)                          \
        g2l16(Kp + ((kt) * 16 + 2 * p) * 256 + lane * 8,                   \
              kbuf + (half) * 8320 + p * 1040);                            \
  }
#define CONSUME_K(kt, half)                                                \
  {                                                                        \
    _Pragma("unroll") for (int cs = 0; cs < 8; cs++) {                     \
      short8 kf = *(const short8*)(kbuf + (half) * 8320 + (l15 >> 1) * 1040 \
                                   + (l15 & 1) * 512 + quad * 16 + cs * 64); \
      acc[kt] = __builtin_amdgcn_mfma_f32_16x16x32_bf16(kf, qf[cs],        \
                                                        acc[kt], 0, 0, 0); \
    }                                                                      \
  }

  STAGE_K(0, 0);
#pragma unroll
  for (int kt = 0; kt < 15; kt++) {
    STAGE_K(kt + 1, (kt + 1) & 1);
    __builtin_amdgcn_s_waitcnt(WC_VM8);   // oldest 8 (chunk kt) arrived
    CONSUME_K(kt, kt & 1);
  }
  __builtin_amdgcn_s_waitcnt(WC_VM0);
  CONSUME_K(15, 1);

  // ---- dis: coalesced stage into wave buffer, consume as b128 frags ----
  const float* Dp = dis + ((size_t)b * N_ + q0) * N_ + w * 256;
#pragma unroll
  for (int r = 0; r < 16; r++)
    g2l16(Dp + (size_t)r * N_ + lane * 4, kbuf + r * 1040);
  __builtin_amdgcn_s_waitcnt(WC_VM0);
#pragma unroll
  for (int kt = 0; kt < 16; kt++) {
    f32x4 dv = *(const f32x4*)(kbuf + l15 * 1040 + kt * 64 + quad * 16);
#pragma unroll
    for (int r = 0; r < 4; r++) acc[kt][r] = (acc[kt][r] + dv[r]) * 0.0625f;
  }

  // ---- mask: same staging path; apply + row max ----
  const int* Mp = mask + ((size_t)b * N_ + q0) * N_ + w * 256;
#pragma unroll
  for (int r = 0; r < 16; r++)
    g2l16(Mp + (size_t)r * N_ + lane * 4, kbuf + r * 1040);
  __builtin_amdgcn_s_waitcnt(WC_VM0);
  float m = -3.0e38f;
#pragma unroll
  for (int kt = 0; kt < 16; kt++) {
    i32x4 mv = *(const i32x4*)(kbuf + l15 * 1040 + kt * 64 + quad * 16);
#pragma unroll
    for (int r = 0; r < 4; r++) {
      acc[kt][r] = mv[r] ? -3.0e38f : acc[kt][r];
      m = fmaxf(m, acc[kt][r]);
    }
  }

  // ---- softmax: all 64 values in a lane belong to q=q0+l15 ----
  m = fmaxf(m, __shfl_xor(m, 16));
  m = fmaxf(m, __shfl_xor(m, 32));
  if (lane < 16) redm[w][lane] = m;
  __syncthreads();
  float M = fmaxf(fmaxf(redm[0][l15], redm[1][l15]),
                  fmaxf(redm[2][l15], redm[3][l15]));

  float sum = 0.f;
#pragma unroll
  for (int kt = 0; kt < 16; kt++)
#pragma unroll
    for (int r = 0; r < 4; r++) {
      float e = __expf(acc[kt][r] - M);
      acc[kt][r] = e;
      sum += e;
    }
  sum += __shfl_xor(sum, 16);
  sum += __shfl_xor(sum, 32);
  if (lane < 16) reds[w][lane] = sum;
  __syncthreads();
  float inv = 1.0f / (reds[0][l15] + reds[1][l15] + reds[2][l15] + reds[3][l15]);

  // ---- p_attn (float4 from regs) + P into LDS (A-layout, aliases staging) ----
  size_t base = ((size_t)b * N_ + q0 + l15) * N_ + w * 256 + quad * 4;
#pragma unroll
  for (int kt = 0; kt < 16; kt++) {
    float4 p;
    p.x = acc[kt][0] * inv;
    p.y = acc[kt][1] * inv;
    p.z = acc[kt][2] * inv;
    p.w = acc[kt][3] * inv;
    *(float4*)(p_attn + base + (size_t)kt * 16) = p;
    short4 pb;
    pb.x = f2bf(p.x); pb.y = f2bf(p.y); pb.z = f2bf(p.z); pb.w = f2bf(p.w);
    *(short4*)&P_lds[l15 * PSTRIDE + w * 256 + kt * 16 + quad * 4] = pb;
  }
  __syncthreads();

  // ---- PV: A = P from LDS, B = Vt (direct global frags), cols w*64..w*64+63 ----
  f32x4 o[4];
#pragma unroll
  for (int i = 0; i < 4; i++) o[i] = z;
  const short* Vp = Vt + ((size_t)b * C_ + w * 64 + l15) * N_ + quad * 8;

#pragma unroll 4
  for (int ks = 0; ks < N_; ks += 32) {
    short8 a = *(const short8*)&P_lds[l15 * PSTRIDE + ks + quad * 8];
#pragma unroll
    for (int ct = 0; ct < 4; ct++) {
      short8 bv = *(const short8*)(Vp + (size_t)ct * 16 * N_ + ks);
      o[ct] = __builtin_amdgcn_mfma_f32_16x16x32_bf16(a, bv, o[ct], 0, 0, 0);
    }
  }

#pragma unroll
  for (int ct = 0; ct < 4; ct++)
#pragma unroll
    for (int r = 0; r < 4; r++)
      p_val[((size_t)b * N_ + q0 + quad * 4 + r) * C_ + w * 64 + ct * 16 + l15] =
          o[ct][r];
}

extern "C" void kernel_launch(void* const* d_in, const int* in_sizes, int n_in,
                              void* d_out, int out_size, void* d_ws, size_t ws_size,
                              hipStream_t stream) {
  const float* Q   = (const float*)d_in[0];
  const float* K   = (const float*)d_in[1];
  const float* V   = (const float*)d_in[2];
  const int* mask  = (const int*)d_in[3];
  const float* dis = (const float*)d_in[4];

  float* out = (float*)d_out;
  float* p_val  = out;                          // (B,N,C)
  float* p_attn = out + (size_t)B_ * N_ * C_;   // (B,N,N)

  const size_t nelem = (size_t)B_ * N_ * C_;
  short* Kbf = (short*)d_ws;
  short* Vt  = Kbf + nelem;

  prep_kernel<<<dim3(3072), 256, 0, stream>>>(K, V, Kbf, Vt);
  attn_kernel<<<dim3(B_ * (N_ / 16)), 256, 0, stream>>>(Kbf, Vt, Q, dis, mask,
                                                        p_attn, p_val);
}